// Round 1
// baseline (304.992 us; speedup 1.0000x reference)
//
#include <hip/hip_runtime.h>
#include <stdint.h>

typedef unsigned short u16;

#define B_ 8
#define C_ 64
#define H_ 128
#define W_ 128
#define OC_ 64
#define K_ 9
#define HO_ 128
#define WO_ 128
#define HWC_ (H_*W_*C_)   // elems per batch in NHWC
#define PADW 88           // padded row length (bf16 elems): 176B, 16B-aligned, ~2-way banks

typedef __attribute__((ext_vector_type(8))) short short8;
typedef __attribute__((ext_vector_type(4))) float f32x4;

__device__ __forceinline__ float bf2f(u16 u) {
  union { uint32_t i; float f; } v; v.i = ((uint32_t)u) << 16; return v.f;
}
__device__ __forceinline__ u16 f2bf(float f) {
  union { float f; uint32_t i; } v; v.f = f;
  uint32_t r = v.i + 0x7FFFu + ((v.i >> 16) & 1u);  // RNE
  return (u16)(r >> 16);
}

// ---- prep 1: weight [OC][C][3][3] f32 -> wk [k][oc][c] bf16 ----
__global__ void wprep_kernel(const float* __restrict__ w, u16* __restrict__ wk) {
  int idx = blockIdx.x * 256 + threadIdx.x;
  if (idx < OC_*C_*K_) {
    int k = idx / (OC_*C_);
    int r = idx % (OC_*C_);
    int oc = r >> 6, c = r & 63;
    wk[idx] = f2bf(w[(oc*C_ + c)*9 + k]);
  }
}

// ---- prep 2: input NCHW f32 -> NHWC bf16 ----
__global__ __launch_bounds__(256) void nhwc_kernel(const float* __restrict__ in,
                                                   u16* __restrict__ nhwc) {
  __shared__ float t[64][65];
  const int b = blockIdx.z, h = blockIdx.y, w0 = blockIdx.x * 64;
  const int tid = threadIdx.x;
  for (int idx = tid; idx < 64*64; idx += 256) {
    int c = idx >> 6, w = idx & 63;
    t[w][c] = in[((b*C_ + c)*H_ + h)*W_ + w0 + w];
  }
  __syncthreads();
  for (int idx = tid; idx < 64*64; idx += 256) {
    int w = idx >> 6, c = idx & 63;
    nhwc[((b*H_ + h)*W_ + w0 + w)*C_ + c] = f2bf(t[w][c]);
  }
}

// ---- main: 64px strip x 64oc per block, 4 waves, bf16 MFMA ----
__global__ __launch_bounds__(256) void mdconv_main(
    const float* __restrict__ offs, const float* __restrict__ mask,
    const float* __restrict__ bias, const u16* __restrict__ nhwc,
    const u16* __restrict__ wk, float* __restrict__ out)
{
  __shared__ u16 wlds[64*PADW];
  __shared__ u16 clds[64*PADW];
  __shared__ int params[576*8];

  const int tid = threadIdx.x;
  const int lane = tid & 63;
  const int wv = tid >> 6;
  const int b = blockIdx.z;
  const int p = blockIdx.y;
  const int q0 = blockIdx.x * 64;

  // phase 1: per-(k,px) sampling params -> LDS
  for (int item = tid; item < 576; item += 256) {
    const int k = item >> 6;
    const int px = item & 63;
    const int q = q0 + px;
    const int ky = k / 3, kx = k % 3;
    const float oy = offs[((b*18 + 2*k)*HO_ + p)*WO_ + q];
    const float ox = offs[((b*18 + 2*k + 1)*HO_ + p)*WO_ + q];
    const float mm = mask[((b*9 + k)*HO_ + p)*WO_ + q];
    const float py  = (float)(ky + p - 1) + oy;
    const float pxx = (float)(kx + q - 1) + ox;
    const float y0f = floorf(py), x0f = floorf(pxx);
    const int y0 = (int)y0f, x0 = (int)x0f;
    const int y1 = y0 + 1, x1 = x0 + 1;
    const float wy1 = py - y0f, wx1 = pxx - x0f;
    const float wy0 = 1.f - wy1, wx0 = 1.f - wx1;
    const bool vy0 = (y0 >= 0) & (y0 < H_);
    const bool vy1 = (y1 >= 0) & (y1 < H_);
    const bool vx0 = (x0 >= 0) & (x0 < W_);
    const bool vx1 = (x1 >= 0) & (x1 < W_);
    const float w00 = (vy0 & vx0) ? wy0*wx0*mm : 0.f;
    const float w01 = (vy0 & vx1) ? wy0*wx1*mm : 0.f;
    const float w10 = (vy1 & vx0) ? wy1*wx0*mm : 0.f;
    const float w11 = (vy1 & vx1) ? wy1*wx1*mm : 0.f;
    const int y0c = min(max(y0,0),H_-1), y1c = min(max(y1,0),H_-1);
    const int x0c = min(max(x0,0),W_-1), x1c = min(max(x1,0),W_-1);
    const int base = b * HWC_;
    int* pp = &params[item*8];
    pp[0] = base + (y0c*W_ + x0c)*C_;
    pp[1] = base + (y0c*W_ + x1c)*C_;
    pp[2] = base + (y1c*W_ + x0c)*C_;
    pp[3] = base + (y1c*W_ + x1c)*C_;
    pp[4] = __float_as_int(w00);
    pp[5] = __float_as_int(w01);
    pp[6] = __float_as_int(w10);
    pp[7] = __float_as_int(w11);
  }
  __syncthreads();

  f32x4 acc00 = {0.f,0.f,0.f,0.f};
  f32x4 acc01 = acc00, acc10 = acc00, acc11 = acc00;
  const int wr = wv >> 1, wc = wv & 1;

  const u16* wbase = &wlds[(wr*32 + (lane & 15))*PADW + (lane >> 4)*8];
  const u16* cbase = &clds[(wc*32 + (lane & 15))*PADW + (lane >> 4)*8];

  for (int k = 0; k < 9; ++k) {
    // stage W_k: 64x64 bf16, padded rows
    for (int cid = tid; cid < 512; cid += 256) {
      const int oc = cid >> 3, c8 = cid & 7;
      const uint4 v = *(const uint4*)(wk + k*4096 + oc*64 + c8*8);
      *(uint4*)(&wlds[oc*PADW + c8*8]) = v;
    }
    // build col[px][c]: wave wv owns px = wv*16 .. wv*16+15; lane = c
    for (int j = 0; j < 16; ++j) {
      const int px = wv*16 + j;
      const int4 pa = *(const int4*)(&params[(k*64 + px)*8]);
      const int4 pw = *(const int4*)(&params[(k*64 + px)*8 + 4]);
      const float v00 = bf2f(nhwc[pa.x + lane]);
      const float v01 = bf2f(nhwc[pa.y + lane]);
      const float v10 = bf2f(nhwc[pa.z + lane]);
      const float v11 = bf2f(nhwc[pa.w + lane]);
      const float s = __int_as_float(pw.x)*v00 + __int_as_float(pw.y)*v01
                    + __int_as_float(pw.z)*v10 + __int_as_float(pw.w)*v11;
      clds[px*PADW + lane] = f2bf(s);
    }
    __syncthreads();
    // MFMA: each wave computes 32oc x 32px quadrant
    #pragma unroll
    for (int kk = 0; kk < 2; ++kk) {
      const short8 a0 = *(const short8*)(wbase + kk*32);
      const short8 a1 = *(const short8*)(wbase + 16*PADW + kk*32);
      const short8 b0 = *(const short8*)(cbase + kk*32);
      const short8 b1 = *(const short8*)(cbase + 16*PADW + kk*32);
      acc00 = __builtin_amdgcn_mfma_f32_16x16x32_bf16(a0, b0, acc00, 0, 0, 0);
      acc01 = __builtin_amdgcn_mfma_f32_16x16x32_bf16(a0, b1, acc01, 0, 0, 0);
      acc10 = __builtin_amdgcn_mfma_f32_16x16x32_bf16(a1, b0, acc10, 0, 0, 0);
      acc11 = __builtin_amdgcn_mfma_f32_16x16x32_bf16(a1, b1, acc11, 0, 0, 0);
    }
    if (k < 8) __syncthreads();
  }

  // epilogue: C/D layout col=lane&15 (px), row=(lane>>4)*4+j (oc)
  const int qc = q0 + wc*32 + (lane & 15);
  const int ocr = wr*32 + (lane >> 4)*4;
  #pragma unroll
  for (int m = 0; m < 2; ++m) {
    #pragma unroll
    for (int n = 0; n < 2; ++n) {
      const f32x4 a = (m==0) ? (n==0 ? acc00 : acc01) : (n==0 ? acc10 : acc11);
      #pragma unroll
      for (int j = 0; j < 4; ++j) {
        const int oc = ocr + m*16 + j;
        out[((b*OC_ + oc)*HO_ + p)*WO_ + qc + n*16] = a[j] + bias[oc];
      }
    }
  }
}

extern "C" void kernel_launch(void* const* d_in, const int* in_sizes, int n_in,
                              void* d_out, int out_size, void* d_ws, size_t ws_size,
                              hipStream_t stream) {
  const float* input  = (const float*)d_in[0];
  const float* offset = (const float*)d_in[1];
  const float* mask   = (const float*)d_in[2];
  const float* weight = (const float*)d_in[3];
  const float* bias   = (const float*)d_in[4];
  float* out = (float*)d_out;

  u16* nhwc = (u16*)d_ws;                              // 16 MB
  u16* wk   = nhwc + (size_t)B_*H_*W_*C_;              // 72 KB

  hipLaunchKernelGGL(wprep_kernel, dim3(144), dim3(256), 0, stream, weight, wk);
  hipLaunchKernelGGL(nhwc_kernel, dim3(2, 128, 8), dim3(256), 0, stream, input, nhwc);
  hipLaunchKernelGGL(mdconv_main, dim3(2, 128, 8), dim3(256), 0, stream,
                     offset, mask, bias, nhwc, wk, out);
}

// Round 2
// 60.364 us; speedup vs baseline: 5.0526x; 5.0526x over previous
//
#include <hip/hip_runtime.h>
#include <stdint.h>

typedef unsigned short u16;

#define B_ 8
#define C_ 64
#define H_ 128
#define W_ 128
#define OC_ 64
#define HO_ 128
#define WO_ 128
#define HWC_ (H_*W_*C_)   // elems per batch in NHWC
#define PADW 72           // padded clds row (bf16): 144B, 16B-aligned, 2-way banks max

typedef __attribute__((ext_vector_type(8))) short short8;
typedef __attribute__((ext_vector_type(4))) float f32x4;

__device__ __forceinline__ u16 f2bf(float f) {
  union { float f; uint32_t i; } v; v.f = f;
  uint32_t r = v.i + 0x7FFFu + ((v.i >> 16) & 1u);  // RNE
  return (u16)(r >> 16);
}
__device__ __forceinline__ uint32_t pkbf(float lo, float hi) {
  uint32_t r;
  asm("v_cvt_pk_bf16_f32 %0, %1, %2" : "=v"(r) : "v"(lo), "v"(hi));
  return r;
}
#define BF_LO(u) __uint_as_float((uint32_t)(u) << 16)
#define BF_HI(u) __uint_as_float((uint32_t)(u) & 0xFFFF0000u)

// ---- prep 1: weight [OC][C][3][3] f32 -> wk2 in MFMA A-fragment order ----
// wk2 flat index = (((k*2 + wr)*2 + m)*2 + kk)*512 + lane*8 + j
//   oc = wr*32 + m*16 + (lane&15);  c = kk*32 + (lane>>4)*8 + j
__global__ void wprep_kernel(const float* __restrict__ w, u16* __restrict__ wk2) {
  const int idx = blockIdx.x * 256 + threadIdx.x;   // 144*256 = 36864 exact
  const int j    = idx & 7;
  const int lane = (idx >> 3) & 63;
  const int kk   = (idx >> 9) & 1;
  const int m    = (idx >> 10) & 1;
  const int wr   = (idx >> 11) & 1;
  const int k    = idx >> 12;
  const int oc = wr*32 + m*16 + (lane & 15);
  const int c  = kk*32 + (lane >> 4)*8 + j;
  wk2[idx] = f2bf(w[(oc*C_ + c)*9 + k]);
}

// ---- prep 2: input NCHW f32 -> NHWC bf16 ----
__global__ __launch_bounds__(256) void nhwc_kernel(const float* __restrict__ in,
                                                   u16* __restrict__ nhwc) {
  __shared__ float t[64][65];
  const int b = blockIdx.z, h = blockIdx.y, w0 = blockIdx.x * 64;
  const int tid = threadIdx.x;
  for (int idx = tid; idx < 64*64; idx += 256) {
    int c = idx >> 6, w = idx & 63;
    t[w][c] = in[((b*C_ + c)*H_ + h)*W_ + w0 + w];
  }
  __syncthreads();
  for (int idx = tid; idx < 64*64; idx += 256) {
    int w = idx >> 6, c = idx & 63;
    nhwc[((b*H_ + h)*W_ + w0 + w)*C_ + c] = f2bf(t[w][c]);
  }
}

__device__ __forceinline__ uint32_t blend1(uint32_t g00, uint32_t g01,
                                           uint32_t g10, uint32_t g11, float4 w) {
  float lo = w.x*BF_LO(g00) + w.y*BF_LO(g01) + w.z*BF_LO(g10) + w.w*BF_LO(g11);
  float hi = w.x*BF_HI(g00) + w.y*BF_HI(g01) + w.z*BF_HI(g10) + w.w*BF_HI(g11);
  return pkbf(lo, hi);
}

// ---- main: 64px strip x 64oc per block, 4 waves, bf16 MFMA ----
__global__ __launch_bounds__(256, 4) void mdconv_main(
    const float* __restrict__ offs, const float* __restrict__ mask,
    const float* __restrict__ bias, const u16* __restrict__ nhwc,
    const u16* __restrict__ wk2, float* __restrict__ out)
{
  __shared__ u16 clds[64*PADW];     // 9216 B
  __shared__ int2 pA[576];          // 4608 B  {base, dx|dy<<16}
  __shared__ float4 pW[576];        // 9216 B  corner weights (mask folded)

  const int tid = threadIdx.x;
  const int lane = tid & 63;
  const int wv = tid >> 6;
  const int b = blockIdx.z;
  const int p = blockIdx.y;
  const int q0 = blockIdx.x * 64;

  // phase 1: per-(k,px) sampling params -> LDS
  for (int item = tid; item < 576; item += 256) {
    const int k = item >> 6;
    const int px = item & 63;
    const int q = q0 + px;
    const int ky = k / 3, kx = k % 3;
    const float oy = offs[((b*18 + 2*k)*HO_ + p)*WO_ + q];
    const float ox = offs[((b*18 + 2*k + 1)*HO_ + p)*WO_ + q];
    const float mm = mask[((b*9 + k)*HO_ + p)*WO_ + q];
    const float py  = (float)(ky + p - 1) + oy;
    const float pxx = (float)(kx + q - 1) + ox;
    const float y0f = floorf(py), x0f = floorf(pxx);
    const int y0 = (int)y0f, x0 = (int)x0f;
    const int y1 = y0 + 1, x1 = x0 + 1;
    const float wy1 = py - y0f, wx1 = pxx - x0f;
    const float wy0 = 1.f - wy1, wx0 = 1.f - wx1;
    const bool vy0 = (y0 >= 0) & (y0 < H_);
    const bool vy1 = (y1 >= 0) & (y1 < H_);
    const bool vx0 = (x0 >= 0) & (x0 < W_);
    const bool vx1 = (x1 >= 0) & (x1 < W_);
    const float w00 = (vy0 & vx0) ? wy0*wx0*mm : 0.f;
    const float w01 = (vy0 & vx1) ? wy0*wx1*mm : 0.f;
    const float w10 = (vy1 & vx0) ? wy1*wx0*mm : 0.f;
    const float w11 = (vy1 & vx1) ? wy1*wx1*mm : 0.f;
    const int y0c = min(max(y0,0),H_-1), y1c = min(max(y1,0),H_-1);
    const int x0c = min(max(x0,0),W_-1), x1c = min(max(x1,0),W_-1);
    // invalid corners have zero weight, so clamped deltas are always safe
    const int dx = (x1c - x0c) * C_;        // 0 or 64
    const int dy = (y1c - y0c) * W_ * C_;   // 0 or 8192
    pA[item] = make_int2(b*HWC_ + (y0c*W_ + x0c)*C_, dx | (dy << 16));
    pW[item] = make_float4(w00, w01, w10, w11);
  }
  __syncthreads();

  f32x4 acc00 = {0.f,0.f,0.f,0.f};
  f32x4 acc01 = acc00, acc10 = acc00, acc11 = acc00;
  const int wr = wv >> 1, wc = wv & 1;
  const u16* cb = &clds[(wc*32 + (lane & 15))*PADW + (lane >> 4)*8];
  const int px0 = tid >> 3;          // 0..31 (second item: +32)
  const int c8 = (tid & 7) * 8;      // channel chunk start

  for (int k = 0; k < 9; ++k) {
    // W fragments straight from global (L2-resident, coalesced); used after barrier
    const u16* wg = wk2 + (k*2 + wr)*2048 + lane*8;
    const short8 a00 = *(const short8*)(wg);
    const short8 a01 = *(const short8*)(wg + 512);
    const short8 a10 = *(const short8*)(wg + 1024);
    const short8 a11 = *(const short8*)(wg + 1536);

    // col build: 2 items/thread, 8 independent 16B gathers in flight
    {
      const int piA = k*64 + px0, piB = piA + 32;
      const int2 aA = pA[piA];
      const int2 aB = pA[piB];
      const float4 wA = pW[piA];
      const float4 wB = pW[piB];
      const u16* sA = nhwc + aA.x + c8;
      const u16* sB = nhwc + aB.x + c8;
      const int dxA = aA.y & 0xFFFF, dyA = ((uint32_t)aA.y) >> 16;
      const int dxB = aB.y & 0xFFFF, dyB = ((uint32_t)aB.y) >> 16;
      const uint4 gA00 = *(const uint4*)(sA);
      const uint4 gA01 = *(const uint4*)(sA + dxA);
      const uint4 gA10 = *(const uint4*)(sA + dyA);
      const uint4 gA11 = *(const uint4*)(sA + dyA + dxA);
      const uint4 gB00 = *(const uint4*)(sB);
      const uint4 gB01 = *(const uint4*)(sB + dxB);
      const uint4 gB10 = *(const uint4*)(sB + dyB);
      const uint4 gB11 = *(const uint4*)(sB + dyB + dxB);
      uint4 rA, rB;
      rA.x = blend1(gA00.x, gA01.x, gA10.x, gA11.x, wA);
      rA.y = blend1(gA00.y, gA01.y, gA10.y, gA11.y, wA);
      rA.z = blend1(gA00.z, gA01.z, gA10.z, gA11.z, wA);
      rA.w = blend1(gA00.w, gA01.w, gA10.w, gA11.w, wA);
      rB.x = blend1(gB00.x, gB01.x, gB10.x, gB11.x, wB);
      rB.y = blend1(gB00.y, gB01.y, gB10.y, gB11.y, wB);
      rB.z = blend1(gB00.z, gB01.z, gB10.z, gB11.z, wB);
      rB.w = blend1(gB00.w, gB01.w, gB10.w, gB11.w, wB);
      *(uint4*)(&clds[px0*PADW + c8]) = rA;
      *(uint4*)(&clds[(px0+32)*PADW + c8]) = rB;
    }
    __syncthreads();

    const short8 b00 = *(const short8*)(cb);
    const short8 b01 = *(const short8*)(cb + 32);
    const short8 b10 = *(const short8*)(cb + 16*PADW);
    const short8 b11 = *(const short8*)(cb + 16*PADW + 32);
    acc00 = __builtin_amdgcn_mfma_f32_16x16x32_bf16(a00, b00, acc00, 0, 0, 0);
    acc00 = __builtin_amdgcn_mfma_f32_16x16x32_bf16(a01, b01, acc00, 0, 0, 0);
    acc01 = __builtin_amdgcn_mfma_f32_16x16x32_bf16(a00, b10, acc01, 0, 0, 0);
    acc01 = __builtin_amdgcn_mfma_f32_16x16x32_bf16(a01, b11, acc01, 0, 0, 0);
    acc10 = __builtin_amdgcn_mfma_f32_16x16x32_bf16(a10, b00, acc10, 0, 0, 0);
    acc10 = __builtin_amdgcn_mfma_f32_16x16x32_bf16(a11, b01, acc10, 0, 0, 0);
    acc11 = __builtin_amdgcn_mfma_f32_16x16x32_bf16(a10, b10, acc11, 0, 0, 0);
    acc11 = __builtin_amdgcn_mfma_f32_16x16x32_bf16(a11, b11, acc11, 0, 0, 0);
    if (k < 8) __syncthreads();
  }

  // epilogue: C/D layout col=lane&15 (px), row=(lane>>4)*4+j (oc)
  const int qc = q0 + wc*32 + (lane & 15);
  const int ocr = wr*32 + (lane >> 4)*4;
  #pragma unroll
  for (int m = 0; m < 2; ++m) {
    #pragma unroll
    for (int n = 0; n < 2; ++n) {
      const f32x4 a = (m==0) ? (n==0 ? acc00 : acc01) : (n==0 ? acc10 : acc11);
      #pragma unroll
      for (int j = 0; j < 4; ++j) {
        const int oc = ocr + m*16 + j;
        out[((b*OC_ + oc)*HO_ + p)*WO_ + qc + n*16] = a[j] + bias[oc];
      }
    }
  }
}

extern "C" void kernel_launch(void* const* d_in, const int* in_sizes, int n_in,
                              void* d_out, int out_size, void* d_ws, size_t ws_size,
                              hipStream_t stream) {
  const float* input  = (const float*)d_in[0];
  const float* offset = (const float*)d_in[1];
  const float* mask   = (const float*)d_in[2];
  const float* weight = (const float*)d_in[3];
  const float* bias   = (const float*)d_in[4];
  float* out = (float*)d_out;

  u16* nhwc = (u16*)d_ws;                              // 16 MB
  u16* wk2  = nhwc + (size_t)B_*H_*W_*C_;              // 72 KB

  hipLaunchKernelGGL(wprep_kernel, dim3(144), dim3(256), 0, stream, weight, wk2);
  hipLaunchKernelGGL(nhwc_kernel, dim3(2, 128, 8), dim3(256), 0, stream, input, nhwc);
  hipLaunchKernelGGL(mdconv_main, dim3(2, 128, 8), dim3(256), 0, stream,
                     offset, mask, bias, nhwc, wk2, out);
}

// Round 3
// 59.371 us; speedup vs baseline: 5.1370x; 1.0167x over previous
//
#include <hip/hip_runtime.h>
#include <stdint.h>

typedef unsigned short u16;

#define B_ 8
#define C_ 64
#define H_ 128
#define W_ 128
#define OC_ 64
#define HO_ 128
#define WO_ 128
#define HWC_ (H_*W_*C_)   // elems per batch in NHWC
#define PADW 72           // padded clds row (bf16): 144B, 16B-aligned

typedef __attribute__((ext_vector_type(8))) short short8;
typedef __attribute__((ext_vector_type(4))) float f32x4;

__device__ __forceinline__ u16 f2bf(float f) {
  union { float f; uint32_t i; } v; v.f = f;
  uint32_t r = v.i + 0x7FFFu + ((v.i >> 16) & 1u);  // RNE
  return (u16)(r >> 16);
}
__device__ __forceinline__ uint32_t pkbf(float lo, float hi) {
  uint32_t r;
  asm("v_cvt_pk_bf16_f32 %0, %1, %2" : "=v"(r) : "v"(lo), "v"(hi));
  return r;
}
#define BF_LO(u) __uint_as_float((uint32_t)(u) << 16)
#define BF_HI(u) __uint_as_float((uint32_t)(u) & 0xFFFF0000u)

// ---- prep 1: weight [OC][C][3][3] f32 -> wk2 in MFMA A-fragment order ----
// wk2 flat index = (((k*2 + wr)*2 + m)*2 + kk)*512 + lane*8 + j
//   oc = wr*32 + m*16 + (lane&15);  c = kk*32 + (lane>>4)*8 + j
__global__ void wprep_kernel(const float* __restrict__ w, u16* __restrict__ wk2) {
  const int idx = blockIdx.x * 256 + threadIdx.x;   // 144*256 = 36864 exact
  const int j    = idx & 7;
  const int lane = (idx >> 3) & 63;
  const int kk   = (idx >> 9) & 1;
  const int m    = (idx >> 10) & 1;
  const int wr   = (idx >> 11) & 1;
  const int k    = idx >> 12;
  const int oc = wr*32 + m*16 + (lane & 15);
  const int c  = kk*32 + (lane >> 4)*8 + j;
  wk2[idx] = f2bf(w[(oc*C_ + c)*9 + k]);
}

// ---- prep 2: input NCHW f32 -> NHWC bf16 ----
__global__ __launch_bounds__(256) void nhwc_kernel(const float* __restrict__ in,
                                                   u16* __restrict__ nhwc) {
  __shared__ float t[64][65];
  const int b = blockIdx.z, h = blockIdx.y, w0 = blockIdx.x * 64;
  const int tid = threadIdx.x;
  for (int idx = tid; idx < 64*64; idx += 256) {
    int c = idx >> 6, w = idx & 63;
    t[w][c] = in[((b*C_ + c)*H_ + h)*W_ + w0 + w];
  }
  __syncthreads();
  for (int idx = tid; idx < 64*64; idx += 256) {
    int w = idx >> 6, c = idx & 63;
    nhwc[((b*H_ + h)*W_ + w0 + w)*C_ + c] = f2bf(t[w][c]);
  }
}

__device__ __forceinline__ uint32_t blend1(uint32_t g00, uint32_t g01,
                                           uint32_t g10, uint32_t g11, float4 w) {
  float lo = w.x*BF_LO(g00) + w.y*BF_LO(g01) + w.z*BF_LO(g10) + w.w*BF_LO(g11);
  float hi = w.x*BF_HI(g00) + w.y*BF_HI(g01) + w.z*BF_HI(g10) + w.w*BF_HI(g11);
  return pkbf(lo, hi);
}

// ---- main: 64px strip x 64oc per block, 4 waves, bf16 MFMA,
//      double-buffered col LDS, 1 barrier per k (2-phase pipeline) ----
__global__ __launch_bounds__(256, 4) void mdconv_main(
    const float* __restrict__ offs, const float* __restrict__ mask,
    const float* __restrict__ bias, const u16* __restrict__ nhwc,
    const u16* __restrict__ wk2, float* __restrict__ out)
{
  __shared__ u16 clds[2][64*PADW];  // 18432 B
  __shared__ int2 pA[576];          //  4608 B  {base, dx|dy<<16}
  __shared__ float4 pW[576];        //  9216 B  corner weights (mask folded)

  const int tid = threadIdx.x;
  const int lane = tid & 63;
  const int wv = tid >> 6;
  const int b = blockIdx.z;
  const int p = blockIdx.y;
  const int q0 = blockIdx.x * 64;

  // phase 1: per-(k,px) sampling params -> LDS
  for (int item = tid; item < 576; item += 256) {
    const int k = item >> 6;
    const int px = item & 63;
    const int q = q0 + px;
    const int ky = k / 3, kx = k % 3;
    const float oy = offs[((b*18 + 2*k)*HO_ + p)*WO_ + q];
    const float ox = offs[((b*18 + 2*k + 1)*HO_ + p)*WO_ + q];
    const float mm = mask[((b*9 + k)*HO_ + p)*WO_ + q];
    const float py  = (float)(ky + p - 1) + oy;
    const float pxx = (float)(kx + q - 1) + ox;
    const float y0f = floorf(py), x0f = floorf(pxx);
    const int y0 = (int)y0f, x0 = (int)x0f;
    const int y1 = y0 + 1, x1 = x0 + 1;
    const float wy1 = py - y0f, wx1 = pxx - x0f;
    const float wy0 = 1.f - wy1, wx0 = 1.f - wx1;
    const bool vy0 = (y0 >= 0) & (y0 < H_);
    const bool vy1 = (y1 >= 0) & (y1 < H_);
    const bool vx0 = (x0 >= 0) & (x0 < W_);
    const bool vx1 = (x1 >= 0) & (x1 < W_);
    const float w00 = (vy0 & vx0) ? wy0*wx0*mm : 0.f;
    const float w01 = (vy0 & vx1) ? wy0*wx1*mm : 0.f;
    const float w10 = (vy1 & vx0) ? wy1*wx0*mm : 0.f;
    const float w11 = (vy1 & vx1) ? wy1*wx1*mm : 0.f;
    const int y0c = min(max(y0,0),H_-1), y1c = min(max(y1,0),H_-1);
    const int x0c = min(max(x0,0),W_-1), x1c = min(max(x1,0),W_-1);
    // invalid corners have zero weight, so clamped deltas are always safe
    const int dx = (x1c - x0c) * C_;        // 0 or 64
    const int dy = (y1c - y0c) * W_ * C_;   // 0 or 8192
    pA[item] = make_int2(b*HWC_ + (y0c*W_ + x0c)*C_, dx | (dy << 16));
    pW[item] = make_float4(w00, w01, w10, w11);
  }
  __syncthreads();

  f32x4 acc00 = {0.f,0.f,0.f,0.f};
  f32x4 acc01 = acc00, acc10 = acc00, acc11 = acc00;
  const int wr = wv >> 1, wc = wv & 1;
  const int px0 = tid >> 3;          // 0..31 (second item: +32)
  const int c8 = (tid & 7) * 8;      // channel chunk start

  short8 a00, a01, a10, a11;         // A-frags for current k
  short8 n00, n01, n10, n11;         // prefetched A-frags for k+1
  uint4 gA00, gA01, gA10, gA11, gB00, gB01, gB10, gB11;
  float4 wAx, wBx;

#define GATHER(kk_) { \
    const int piA = (kk_)*64 + px0, piB = piA + 32; \
    const int2 aA = pA[piA]; const int2 aB = pA[piB]; \
    wAx = pW[piA]; wBx = pW[piB]; \
    const u16* sA = nhwc + aA.x + c8; \
    const u16* sB = nhwc + aB.x + c8; \
    const int dxA = aA.y & 0xFFFF, dyA = ((uint32_t)aA.y) >> 16; \
    const int dxB = aB.y & 0xFFFF, dyB = ((uint32_t)aB.y) >> 16; \
    gA00 = *(const uint4*)(sA);       gA01 = *(const uint4*)(sA + dxA); \
    gA10 = *(const uint4*)(sA + dyA); gA11 = *(const uint4*)(sA + dyA + dxA); \
    gB00 = *(const uint4*)(sB);       gB01 = *(const uint4*)(sB + dxB); \
    gB10 = *(const uint4*)(sB + dyB); gB11 = *(const uint4*)(sB + dyB + dxB); }

#define LOADA(kk_, d00, d01, d10, d11) { \
    const u16* wg = wk2 + ((kk_)*2 + wr)*2048 + lane*8; \
    d00 = *(const short8*)(wg);        d01 = *(const short8*)(wg + 512); \
    d10 = *(const short8*)(wg + 1024); d11 = *(const short8*)(wg + 1536); }

#define BLEND_WRITE(buf_) { \
    uint4 rA, rB; \
    rA.x = blend1(gA00.x, gA01.x, gA10.x, gA11.x, wAx); \
    rA.y = blend1(gA00.y, gA01.y, gA10.y, gA11.y, wAx); \
    rA.z = blend1(gA00.z, gA01.z, gA10.z, gA11.z, wAx); \
    rA.w = blend1(gA00.w, gA01.w, gA10.w, gA11.w, wAx); \
    rB.x = blend1(gB00.x, gB01.x, gB10.x, gB11.x, wBx); \
    rB.y = blend1(gB00.y, gB01.y, gB10.y, gB11.y, wBx); \
    rB.z = blend1(gB00.z, gB01.z, gB10.z, gB11.z, wBx); \
    rB.w = blend1(gB00.w, gB01.w, gB10.w, gB11.w, wBx); \
    *(uint4*)(&clds[buf_][px0*PADW + c8]) = rA; \
    *(uint4*)(&clds[buf_][(px0+32)*PADW + c8]) = rB; }

  // prologue: stage k=0
  GATHER(0);
  LOADA(0, a00, a01, a10, a11);
  BLEND_WRITE(0);
  __syncthreads();

  const u16* cb0 = &clds[0][(wc*32 + (lane & 15))*PADW + (lane >> 4)*8];
  const u16* cb1 = &clds[1][(wc*32 + (lane & 15))*PADW + (lane >> 4)*8];

#pragma unroll
  for (int k = 0; k < 9; ++k) {
    if (k < 8) {
      GATHER(k+1);                      // VMEM in flight across MFMA
      LOADA(k+1, n00, n01, n10, n11);
    }
    const u16* cb = (k & 1) ? cb1 : cb0;
    const short8 b00 = *(const short8*)(cb);
    const short8 b01 = *(const short8*)(cb + 32);
    const short8 b10 = *(const short8*)(cb + 16*PADW);
    const short8 b11 = *(const short8*)(cb + 16*PADW + 32);
    acc00 = __builtin_amdgcn_mfma_f32_16x16x32_bf16(a00, b00, acc00, 0, 0, 0);
    acc00 = __builtin_amdgcn_mfma_f32_16x16x32_bf16(a01, b01, acc00, 0, 0, 0);
    acc01 = __builtin_amdgcn_mfma_f32_16x16x32_bf16(a00, b10, acc01, 0, 0, 0);
    acc01 = __builtin_amdgcn_mfma_f32_16x16x32_bf16(a01, b11, acc01, 0, 0, 0);
    acc10 = __builtin_amdgcn_mfma_f32_16x16x32_bf16(a10, b00, acc10, 0, 0, 0);
    acc10 = __builtin_amdgcn_mfma_f32_16x16x32_bf16(a11, b01, acc10, 0, 0, 0);
    acc11 = __builtin_amdgcn_mfma_f32_16x16x32_bf16(a10, b10, acc11, 0, 0, 0);
    acc11 = __builtin_amdgcn_mfma_f32_16x16x32_bf16(a11, b11, acc11, 0, 0, 0);
    if (k < 8) {
      BLEND_WRITE((k+1) & 1);
      __syncthreads();
      a00 = n00; a01 = n01; a10 = n10; a11 = n11;
    }
  }

  // epilogue: C/D layout col=lane&15 (px), row=(lane>>4)*4+j (oc)
  const int qc = q0 + wc*32 + (lane & 15);
  const int ocr = wr*32 + (lane >> 4)*4;
  #pragma unroll
  for (int m = 0; m < 2; ++m) {
    #pragma unroll
    for (int n = 0; n < 2; ++n) {
      const f32x4 a = (m==0) ? (n==0 ? acc00 : acc01) : (n==0 ? acc10 : acc11);
      #pragma unroll
      for (int j = 0; j < 4; ++j) {
        const int oc = ocr + m*16 + j;
        out[((b*OC_ + oc)*HO_ + p)*WO_ + qc + n*16] = a[j] + bias[oc];
      }
    }
  }
}

extern "C" void kernel_launch(void* const* d_in, const int* in_sizes, int n_in,
                              void* d_out, int out_size, void* d_ws, size_t ws_size,
                              hipStream_t stream) {
  const float* input  = (const float*)d_in[0];
  const float* offset = (const float*)d_in[1];
  const float* mask   = (const float*)d_in[2];
  const float* weight = (const float*)d_in[3];
  const float* bias   = (const float*)d_in[4];
  float* out = (float*)d_out;

  u16* nhwc = (u16*)d_ws;                              // 16 MB
  u16* wk2  = nhwc + (size_t)B_*H_*W_*C_;              // 72 KB

  hipLaunchKernelGGL(wprep_kernel, dim3(144), dim3(256), 0, stream, weight, wk2);
  hipLaunchKernelGGL(nhwc_kernel, dim3(2, 128, 8), dim3(256), 0, stream, input, nhwc);
  hipLaunchKernelGGL(mdconv_main, dim3(2, 128, 8), dim3(256), 0, stream,
                     offset, mask, bias, nhwc, wk2, out);
}